// Round 20
// baseline (212.696 us; speedup 1.0000x reference)
//
#include <hip/hip_runtime.h>
#include <hip/hip_bf16.h>
#include <math.h>

#define N_   1024
#define S_   256
#define D_   256
#define C_   256
#define R_   64
#define CLS_ 1000
#define INV16 0.0625f

typedef unsigned short ushortT;
typedef unsigned int uint32;
typedef short bf8 __attribute__((ext_vector_type(8)));
typedef float f4 __attribute__((ext_vector_type(4)));

static __device__ __forceinline__ float bf2f(uint32 u){
  return __uint_as_float(u << 16);
}
static __device__ __forceinline__ ushortT f2bf(float f){
  uint32 x = __float_as_uint(f);
  uint32 r = x + 0x7FFFu + ((x >> 16) & 1u);
  return (ushortT)(r >> 16);
}
static __device__ __forceinline__ uint32 packbf(float a, float b){
  return ((uint32)f2bf(b) << 16) | (uint32)f2bf(a);
}
static __device__ __forceinline__ float wred_max(float v){
  for (int o = 32; o; o >>= 1) v = fmaxf(v, __shfl_xor(v, o));
  return v;
}
static __device__ __forceinline__ float wred_sum(float v){
  for (int o = 32; o; o >>= 1) v += __shfl_xor(v, o);
  return v;
}
// swizzled byte offset inside a [rows][256]-bf16 LDS tile (row stride 512B)
static __device__ __forceinline__ int swz(int row, int colbyte){
  return row*512 + ((colbyte & ~15) ^ ((row & 7) << 4)) + (colbyte & 15);
}
// fragment-ready packed index for a [rows x 256] matrix, 16-row frags, K-step 32
static __device__ __forceinline__ int pkidx(int row, int col, int nfrag){
  int ks = col >> 5, hi = (col >> 3) & 3, e = col & 7;
  int frag = row >> 4, l15p = row & 15;
  return ((ks*nfrag + frag)*64 + hi*16 + l15p)*8 + e;
}

// ---------------- K0: weight prep + MT = cb @ rcb^T + sum_ws zero -------------
__global__ __launch_bounds__(256) void k0(const float* __restrict__ cb,
    const float* __restrict__ rcb, const float* __restrict__ Wc,
    const float* __restrict__ Wr, ushortT* __restrict__ a1pk,
    ushortT* __restrict__ Wcr_bf, float* __restrict__ MT_f32,
    ushortT* __restrict__ mtpk, float* __restrict__ sum_ws)
{
  __shared__ float rl[D_];
  int bid = blockIdx.x, t = threadIdx.x;
  int gtid = bid*256 + t;
  int stride = gridDim.x*256;
  for (int e = gtid; e < (C_ + R_)*D_; e += stride){
    int row = e >> 8, col = e & 255;
    float v = (row < C_) ? cb[e] : rcb[e - C_*D_];
    a1pk[pkidx(row, col, 20)] = f2bf(v);
  }
  for (int e = gtid; e < CLS_*D_; e += stride) Wcr_bf[e] = f2bf(Wc[e]);
  for (int e = gtid; e < D_*D_; e += stride)  Wcr_bf[CLS_*D_ + e] = f2bf(Wr[e]);
  for (int e = gtid; e < 24*D_; e += stride)  Wcr_bf[1256*D_ + e] = 0;
  for (int e = gtid; e < N_*D_; e += stride)  sum_ws[e] = 0.f;

  if (bid < R_){
    rl[t] = rcb[bid*D_ + t];
    __syncthreads();
    float acc = 0.f;
    const float* crow = cb + t*D_;
    #pragma unroll 8
    for (int k = 0; k < D_; k += 4){
      float4 w = *(const float4*)(crow + k);
      acc += w.x*rl[k] + w.y*rl[k+1] + w.z*rl[k+2] + w.w*rl[k+3];
    }
    MT_f32[bid*C_ + t] = acc;
    mtpk[pkidx(bid, t, 4)] = f2bf(acc);
  }
}

// ---------------- K1: per-query pass, batched x4 ------------------------------
#define G4 4
__global__ __launch_bounds__(256) void k1(const float* __restrict__ q,
    const float* __restrict__ cb, const float* __restrict__ rcb,
    const float* __restrict__ Wq, const float* __restrict__ MT_f32,
    float* __restrict__ cw_ws, float* __restrict__ rcw_ws)
{
  __shared__ float qv[G4][D_], qp[G4][D_], cwl[G4][C_];
  __shared__ float redA[G4][4], redB2[G4][4];
  int n0 = blockIdx.x*G4, t = threadIdx.x;
  #pragma unroll
  for (int g = 0; g < G4; g++) qv[g][t] = q[(n0+g)*D_ + t];
  __syncthreads();
  {
    float acc[G4] = {0.f,0.f,0.f,0.f};
    const float* wrow = Wq + t*D_;
    #pragma unroll 4
    for (int k = 0; k < D_; k += 4){
      float4 w = *(const float4*)(wrow + k);
      #pragma unroll
      for (int g = 0; g < G4; g++)
        acc[g] += qv[g][k]*w.x + qv[g][k+1]*w.y + qv[g][k+2]*w.z + qv[g][k+3]*w.w;
    }
    #pragma unroll
    for (int g = 0; g < G4; g++) qp[g][t] = acc[g];
  }
  __syncthreads();
  float L[G4] = {0.f,0.f,0.f,0.f};
  {
    const float* crow = cb + t*D_;
    #pragma unroll 4
    for (int k = 0; k < D_; k += 4){
      float4 w = *(const float4*)(crow + k);
      #pragma unroll
      for (int g = 0; g < G4; g++)
        L[g] += qp[g][k]*w.x + qp[g][k+1]*w.y + qp[g][k+2]*w.z + qp[g][k+3]*w.w;
    }
  }
  float m[G4], e[G4], s[G4];
  #pragma unroll
  for (int g = 0; g < G4; g++){ L[g] *= INV16; m[g] = wred_max(L[g]); }
  if ((t & 63) == 0)
    #pragma unroll
    for (int g = 0; g < G4; g++) redA[g][t >> 6] = m[g];
  __syncthreads();
  #pragma unroll
  for (int g = 0; g < G4; g++){
    m[g] = fmaxf(fmaxf(redA[g][0], redA[g][1]), fmaxf(redA[g][2], redA[g][3]));
    e[g] = __expf(L[g] - m[g]);
    s[g] = wred_sum(e[g]);
  }
  if ((t & 63) == 0)
    #pragma unroll
    for (int g = 0; g < G4; g++) redB2[g][t >> 6] = s[g];
  __syncthreads();
  #pragma unroll
  for (int g = 0; g < G4; g++){
    float ss = redB2[g][0] + redB2[g][1] + redB2[g][2] + redB2[g][3];
    float w = e[g] / ss;
    cwl[g][t] = w;
    cw_ws[(n0+g)*C_ + t] = w;
  }
  __syncthreads();
  if (t < R_){
    float qd[G4] = {0.f,0.f,0.f,0.f}, md[G4] = {0.f,0.f,0.f,0.f};
    const float* rrow = rcb + t*D_;
    const float* mrow = MT_f32 + t*C_;
    #pragma unroll 4
    for (int k = 0; k < D_; k += 4){
      float4 wv = *(const float4*)(rrow + k);
      float4 mv = *(const float4*)(mrow + k);
      #pragma unroll
      for (int g = 0; g < G4; g++){
        qd[g] += qp[g][k]*wv.x + qp[g][k+1]*wv.y + qp[g][k+2]*wv.z + qp[g][k+3]*wv.w;
        md[g] += cwl[g][k]*mv.x + cwl[g][k+1]*mv.y + cwl[g][k+2]*mv.z + cwl[g][k+3]*mv.w;
      }
    }
    #pragma unroll
    for (int g = 0; g < G4; g++){
      float Lr = (qd[g] - md[g]) * INV16;
      float mr = wred_max(Lr);
      float er = __expf(Lr - mr);
      float sr = wred_sum(er);
      rcw_ws[(n0+g)*R_ + t] = er / sr;
    }
  }
}

// ---------------- K2a: weights + fused V (issue-early), block-reduced atomics -
// block = (n, 32-s tile); 4 waves. Wave w owns: c-frags {w+4f} on both s-frags;
// r-frags {2*(w>>1), +1} on s-frag (w&1); matching MT frags for WM.
// V loads issued BEFORE the exp phase (addresses comb-independent); consumed
// after B4. Block-reduce via Ktile overlay; one wave atomically adds.
__global__ __launch_bounds__(256, 4) void k2a(const float* __restrict__ Kt,
    const float* __restrict__ Vt, const ushortT* __restrict__ a1pk,
    const ushortT* __restrict__ mtpk, const float* __restrict__ cw_ws,
    const float* __restrict__ rcw_ws, const float* __restrict__ rlogit,
    float* __restrict__ sum_ws, float* __restrict__ out_ew)
{
  __shared__ __align__(16) ushortT Ktile[32*256];   // 16 KB (V-partial overlay at end)
  __shared__ __align__(16) ushortT Wtile[32*256];   // 16 KB
  __shared__ float redS[4][32], redW[4][32];        // 1 KB (c-softmax)
  __shared__ float red3S[4][32], red3W[4][32];      // 1 KB (r-softmax)
  __shared__ float combl[32];

  int bx  = blockIdx.x;
  int n   = bx >> 3;
  int s0  = (bx & 7) * 32;
  int tid = threadIdx.x;
  int lane = tid & 63, w = tid >> 6;
  int l15 = lane & 15, l4 = lane >> 4;
  int rp  = w >> 1;          // r-frag pair index (0..1)
  int sjr = w & 1;           // owned s-frag for R-side
  float gate  = 1.f / (1.f + __expf(-rlogit[0]));
  float inv1g = 1.f / (1.f + gate);

  const float* Kn = Kt + (size_t)n*S_*D_ + (size_t)s0*D_;

  // ---- stage K tile (32x256) fp32 -> bf16 swz LDS ----
  #pragma unroll
  for (int j = 0; j < 4; j++){
    int ch = tid + j*256;
    int row = ch >> 5, blk = ch & 31;
    const float* src = Kn + row*D_ + blk*8;
    float4 a = *(const float4*)src;
    float4 b = *(const float4*)(src + 4);
    uint4 wv = {packbf(a.x,a.y), packbf(a.z,a.w), packbf(b.x,b.y), packbf(b.z,b.w)};
    *(uint4*)((char*)Ktile + swz(row, blk*16)) = wv;
  }
  __syncthreads();                                   // B1

  // ---- GEMM1: accC[4 cf][2 sj] + accR[2 rf]; depth-2 A prefetch -------------
  const ushortT* a1b = a1pk + (size_t)lane*8;
  bf8 bnxC[4][2], bnxR[2][2];
  #pragma unroll
  for (int f = 0; f < 4; f++){
    bnxC[f][0] = *(const bf8*)(a1b + (size_t)((        w + 4*f)*64)*8);
    bnxC[f][1] = *(const bf8*)(a1b + (size_t)((20    + w + 4*f)*64)*8);
  }
  #pragma unroll
  for (int i = 0; i < 2; i++){
    bnxR[i][0] = *(const bf8*)(a1b + (size_t)((     16 + 2*rp + i)*64)*8);
    bnxR[i][1] = *(const bf8*)(a1b + (size_t)((20 + 16 + 2*rp + i)*64)*8);
  }
  f4 accC[4][2]; f4 accR[2];
  accR[0] = (f4)0.f; accR[1] = (f4)0.f;
  #pragma unroll
  for (int f = 0; f < 4; f++){ accC[f][0] = (f4)0.f; accC[f][1] = (f4)0.f; }
  #pragma unroll
  for (int ks = 0; ks < 8; ks++){
    bf8 kf0 = *(const bf8*)((const char*)Ktile + swz(     l15, ks*64 + l4*16));
    bf8 kf1 = *(const bf8*)((const char*)Ktile + swz(16 + l15, ks*64 + l4*16));
    bf8 kfr = sjr ? kf1 : kf0;
    #pragma unroll
    for (int f = 0; f < 4; f++){
      bf8 aC = bnxC[f][ks & 1];
      if (ks < 6)
        bnxC[f][ks & 1] = *(const bf8*)(a1b + (size_t)(((ks+2)*20 + w + 4*f)*64)*8);
      accC[f][0] = __builtin_amdgcn_mfma_f32_16x16x32_bf16(aC, kf0, accC[f][0], 0, 0, 0);
      accC[f][1] = __builtin_amdgcn_mfma_f32_16x16x32_bf16(aC, kf1, accC[f][1], 0, 0, 0);
    }
    #pragma unroll
    for (int i = 0; i < 2; i++){
      bf8 aR = bnxR[i][ks & 1];
      if (ks < 6)
        bnxR[i][ks & 1] = *(const bf8*)(a1b + (size_t)(((ks+2)*20 + 16 + 2*rp + i)*64)*8);
      accR[i] = __builtin_amdgcn_mfma_f32_16x16x32_bf16(aR, kfr, accR[i], 0, 0, 0);
    }
  }

  // ---- preload WM's first two MT frag-sets (hidden under exp phase) ---------
  const ushortT* mtb = mtpk + (size_t)lane*8;
  bf8 mnx[2][2];
  #pragma unroll
  for (int i = 0; i < 2; i++){
    mnx[i][0] = *(const bf8*)(mtb + (size_t)((    2*rp + i)*64)*8);
    mnx[i][1] = *(const bf8*)(mtb + (size_t)((4 + 2*rp + i)*64)*8);
  }

  // ---- issue V loads EARLY (consumed after B4; hidden under exp+WM) ---------
  float4 vld[8];
  {
    const float* vp = Vt + (size_t)n*S_*D_ + (size_t)(s0 + w*8)*D_ + lane*4;
    #pragma unroll
    for (int j = 0; j < 8; j++)
      vld[j] = *(const float4*)(vp + (size_t)j*D_);
  }

  // ---- softmax-c partials (exp in place, unnormalized) + Wexp write ---------
  float4 cwv[4];
  #pragma unroll
  for (int f = 0; f < 4; f++)
    cwv[f] = *(const float4*)(cw_ws + n*C_ + (w + 4*f)*16 + l4*4);
  float se[2] = {0,0}, sb[2] = {0,0};
  #pragma unroll
  for (int f = 0; f < 4; f++){
    int cbyte = ((w + 4*f)*16 + l4*4) * 2;
    #pragma unroll
    for (int sj = 0; sj < 2; sj++){
      float e0 = __expf(accC[f][sj][0] * INV16);
      float e1 = __expf(accC[f][sj][1] * INV16);
      float e2 = __expf(accC[f][sj][2] * INV16);
      float e3 = __expf(accC[f][sj][3] * INV16);
      se[sj] += (e0 + e1) + (e2 + e3);
      sb[sj] += e0*cwv[f].x + e1*cwv[f].y + e2*cwv[f].z + e3*cwv[f].w;
      int s_ = sj*16 + l15;
      *(uint32*)((char*)Wtile + swz(s_, cbyte))     = packbf(e0, e1);
      *(uint32*)((char*)Wtile + swz(s_, cbyte + 4)) = packbf(e2, e3);
    }
  }
  #pragma unroll
  for (int sj = 0; sj < 2; sj++){
    se[sj] += __shfl_xor(se[sj], 16); se[sj] += __shfl_xor(se[sj], 32);
    sb[sj] += __shfl_xor(sb[sj], 16); sb[sj] += __shfl_xor(sb[sj], 32);
  }
  if (l4 == 0){
    #pragma unroll
    for (int sj = 0; sj < 2; sj++){
      redS[w][sj*16 + l15] = se[sj];
      redW[w][sj*16 + l15] = sb[sj];
    }
  }
  __syncthreads();                                   // B2 (publishes Wexp + partials)

  float bw_q, rcp_q;
  {
    int sq = sjr*16 + l15;     // for writer waves (w<2) this is the owned col
    float sS = redS[0][sq] + redS[1][sq] + redS[2][sq] + redS[3][sq];
    float sW = redW[0][sq] + redW[1][sq] + redW[2][sq] + redW[3][sq];
    rcp_q = 1.f / sS;
    bw_q  = sW * rcp_q;
  }

  // ---- WM: MT frags {2rp,2rp+1} x Wexp[s-frag sjr]^T; depth-2 from L2 -------
  f4 wm[2]; wm[0] = (f4)0.f; wm[1] = (f4)0.f;
  #pragma unroll
  for (int ks = 0; ks < 8; ks++){
    bf8 wb = *(const bf8*)((const char*)Wtile + swz(sjr*16 + l15, ks*64 + l4*16));
    #pragma unroll
    for (int i = 0; i < 2; i++){
      bf8 a = mnx[i][ks & 1];
      if (ks < 6)
        mnx[i][ks & 1] = *(const bf8*)(mtb + (size_t)(((ks+2)*4 + 2*rp + i)*64)*8);
      wm[i] = __builtin_amdgcn_mfma_f32_16x16x32_bf16(a, wb, wm[i], 0, 0, 0);
    }
  }

  // ---- r-softmax partials: l3 = (accR - wm*rcp_q)/16 ------------------------
  float se3 = 0.f, sc3 = 0.f;
  #pragma unroll
  for (int i = 0; i < 2; i++){
    float4 rv = *(const float4*)(rcw_ws + n*R_ + (2*rp + i)*16 + l4*4);
    float e0 = __expf((accR[i][0] - wm[i][0]*rcp_q) * INV16);
    float e1 = __expf((accR[i][1] - wm[i][1]*rcp_q) * INV16);
    float e2 = __expf((accR[i][2] - wm[i][2]*rcp_q) * INV16);
    float e3 = __expf((accR[i][3] - wm[i][3]*rcp_q) * INV16);
    se3 += (e0 + e1) + (e2 + e3);
    sc3 += e0*rv.x + e1*rv.y + e2*rv.z + e3*rv.w;
  }
  se3 += __shfl_xor(se3, 16); se3 += __shfl_xor(se3, 32);
  sc3 += __shfl_xor(sc3, 16); sc3 += __shfl_xor(sc3, 32);
  if (l4 == 0){
    red3S[w][sjr*16 + l15] = se3;
    red3W[w][sjr*16 + l15] = sc3;
  }
  __syncthreads();                                   // B3

  // ---- combine r-halves + comb write (waves 0,1 own cols w*16+l15) ----------
  if (w < 2){
    int sq = w*16 + l15;
    float sS3 = red3S[w][sq] + red3S[w + 2][sq];
    float sW3 = red3W[w][sq] + red3W[w + 2][sq];
    float comb = bw_q + gate * (sW3 / sS3);
    if (l4 == 0){
      int sabs = n*S_ + s0 + sq;
      out_ew[sabs] = comb * inv1g;
      combl[sq]    = comb;
    }
  }
  __syncthreads();                                   // B4 (combl ready)

  // ---- fused V summary: consume preloaded vld; block-reduce -----------------
  {
    float4 sacc = {0.f, 0.f, 0.f, 0.f};
    #pragma unroll
    for (int j = 0; j < 8; j++){
      float c = combl[w*8 + j];
      float4 v = vld[j];
      sacc.x = fmaf(c, v.x, sacc.x); sacc.y = fmaf(c, v.y, sacc.y);
      sacc.z = fmaf(c, v.z, sacc.z); sacc.w = fmaf(c, v.w, sacc.w);
    }
    float4* sred = (float4*)Ktile;       // Ktile dead after GEMM1; [4][64] float4
    sred[w*64 + lane] = sacc;
  }
  __syncthreads();                                   // B5
  if (tid < 64){
    float4 a0 = ((float4*)Ktile)[tid],       a1 = ((float4*)Ktile)[64 + tid];
    float4 a2 = ((float4*)Ktile)[128 + tid], a3 = ((float4*)Ktile)[192 + tid];
    float* dst = sum_ws + (size_t)n*D_ + tid*4;
    atomicAdd(dst + 0, a0.x + a1.x + a2.x + a3.x);
    atomicAdd(dst + 1, a0.y + a1.y + a2.y + a3.y);
    atomicAdd(dst + 2, a0.z + a1.z + a2.z + a3.z);
    atomicAdd(dst + 3, a0.w + a1.w + a2.w + a3.w);
  }
}

// ---------------- K3: readout GEMM (MFMA, bf16) --------------------------------
__global__ __launch_bounds__(256) void k3(const float* __restrict__ sum_ws,
    const ushortT* __restrict__ Wcr_bf, const float* __restrict__ bc,
    const float* __restrict__ br, float* __restrict__ out)
{
  __shared__ __align__(16) ushortT Stile[64*256];
  int bx = blockIdx.x;
  int ot = bx >> 4;
  int nt = bx & 15;
  int tid = threadIdx.x;
  int lane = tid & 63, wid = tid >> 6;
  int l15 = lane & 15, l4 = lane >> 4;

  const float* Sp = sum_ws + (size_t)nt*64*D_;
  #pragma unroll
  for (int j = 0; j < 8; j++){
    int ch = tid + j*256;
    int row = ch >> 5, blk = ch & 31;
    const float* src = Sp + row*D_ + blk*8;
    float4 a = *(const float4*)src;
    float4 b = *(const float4*)(src + 4);
    uint4 wv = {packbf(a.x,a.y), packbf(a.z,a.w), packbf(b.x,b.y), packbf(b.z,b.w)};
    *(uint4*)((char*)Stile + swz(row, blk*16)) = wv;
  }
  __syncthreads();

  int o0 = ot*64 + wid*16;
  const ushortT* Ap = Wcr_bf + (size_t)(o0 + l15)*D_ + l4*8;
  f4 acc[4];
  #pragma unroll
  for (int j = 0; j < 4; j++) acc[j] = (f4)0.f;
  #pragma unroll
  for (int k = 0; k < 8; k++){
    bf8 a = *(const bf8*)(Ap + k*32);
    #pragma unroll
    for (int nj = 0; nj < 4; nj++){
      bf8 b = *(const bf8*)((const char*)Stile + swz(nj*16 + l15, k*64 + l4*16));
      acc[nj] = __builtin_amdgcn_mfma_f32_16x16x32_bf16(a, b, acc[nj], 0, 0, 0);
    }
  }
  int obase = o0 + l4*4;
  if (obase < 1256){
    float4 bias;
    if (obase < CLS_) bias = *(const float4*)(bc + obase);
    else              bias = *(const float4*)(br + (obase - CLS_));
    #pragma unroll
    for (int nj = 0; nj < 4; nj++){
      int nn = nt*64 + nj*16 + l15;
      float4 v = {acc[nj][0]+bias.x, acc[nj][1]+bias.y, acc[nj][2]+bias.z, acc[nj][3]+bias.w};
      if (obase < CLS_) *(float4*)(out + (size_t)nn*CLS_ + obase) = v;
      else              *(float4*)(out + (size_t)N_*CLS_ + (size_t)nn*D_ + (obase - CLS_)) = v;
    }
  }
}

extern "C" void kernel_launch(void* const* d_in, const int* in_sizes, int n_in,
                              void* d_out, int out_size, void* d_ws, size_t ws_size,
                              hipStream_t stream)
{
  const float* q    = (const float*)d_in[0];
  const float* Kt   = (const float*)d_in[1];
  const float* Vt   = (const float*)d_in[2];
  const float* cb   = (const float*)d_in[3];
  const float* rcb  = (const float*)d_in[4];
  const float* Wq   = (const float*)d_in[5];
  const float* rlg  = (const float*)d_in[6];
  const float* Wc   = (const float*)d_in[7];
  const float* bc   = (const float*)d_in[8];
  const float* Wr   = (const float*)d_in[9];
  const float* br   = (const float*)d_in[10];
  float* out = (float*)d_out;
  float* ws  = (float*)d_ws;

  float* cw_ws   = ws;                          // N*C
  float* rcw_ws  = ws + 262144;                 // N*R
  float* sum_ws  = ws + 327680;                 // N*D
  float* MT_f32  = ws + 851968;                 // R*C
  ushortT* a1pk   = (ushortT*)(ws + 868352);    // 320*D frag-packed
  ushortT* mtpk   = a1pk + (C_ + R_)*D_;        // R*C frag-packed
  ushortT* Wcr_bf = mtpk + R_*C_;               // 1280*D (Wc ; Wr ; zero pad)

  float* out_logits = out;
  float* out_ew     = out + (size_t)N_*CLS_ + (size_t)N_*D_;

  k0 <<<128,   256, 0, stream>>>(cb, rcb, Wc, Wr, a1pk, Wcr_bf, MT_f32, mtpk, sum_ws);
  k1 <<<N_/G4, 256, 0, stream>>>(q, cb, rcb, Wq, MT_f32, cw_ws, rcw_ws);
  k2a<<<N_*8,  256, 0, stream>>>(Kt, Vt, a1pk, mtpk, cw_ws, rcw_ws, rlg, sum_ws, out_ew);
  k3 <<<320,   256, 0, stream>>>(sum_ws, Wcr_bf, bc, br, out_logits);
}